// Round 1
// baseline (727.020 us; speedup 1.0000x reference)
//
#include <hip/hip_runtime.h>
#include <math.h>

// CapsuleLayer dynamic routing, MI355X.
// B=4096, L=200, Din=Dout=64, K=8, 3 iterations.
//
// ws layout (floats):
//   ln      [B*L*64]  = 52,428,800   (low_new = lc @ S, materialized once)
//   Bc      [K*L]     = 1,600        (routing logits, updated per iteration)
//   partial [B*K*L]   = 6,553,600    (per-batch delta partials, tree-reduced)
// total ~225 MB of d_ws.

#define B_SZ  4096
#define L_SZ  200
#define DINK  64
#define DOUTK 64
#define K_SZ  8

// ---------------------------------------------------------------- init Bc
__global__ __launch_bounds__(256) void k_init(const float* __restrict__ Bm,
                                              float* __restrict__ Bc) {
    int i = blockIdx.x * 256 + threadIdx.x;
    if (i < K_SZ * L_SZ) Bc[i] = Bm[i];
}

// ------------------------------------------------- ln = lc @ S  (f32 VALU)
// grid 12800 blocks x 256 threads; each block does 64 rows.
__global__ __launch_bounds__(256) void k_matmul(const float* __restrict__ lc,
                                                const float* __restrict__ S,
                                                float* __restrict__ ln) {
    __shared__ float sS[64][64];   // stride 64 floats: float4-aligned rows
    __shared__ float sA[64][65];   // +1 pad: a-reads hit 4 distinct banks
    int t = threadIdx.x;
    long base = (long)blockIdx.x * 64 * 64;

    {   // stage S (L2-hit after first blocks)
        const float4* S4 = (const float4*)S;
        float4* d = (float4*)&sS[0][0];
        for (int j = t; j < 1024; j += 256) d[j] = S4[j];
    }
    {   // stage lc tile, coalesced float4, scalar-scatter into padded rows
        const float4* p = (const float4*)(lc + base);
        for (int j = t; j < 1024; j += 256) {
            float4 v = p[j];
            int f = j * 4; int r = f >> 6; int c = f & 63;
            sA[r][c] = v.x; sA[r][c+1] = v.y; sA[r][c+2] = v.z; sA[r][c+3] = v.w;
        }
    }
    __syncthreads();

    int o0 = (t & 15) * 4;   // 4 output cols
    int r0 = t >> 4;         // 4 rows: r0, r0+16, r0+32, r0+48
    float4 acc[4] = {};
    for (int k = 0; k < 64; ++k) {
        float4 s4 = *(const float4*)&sS[k][o0];
        #pragma unroll
        for (int i = 0; i < 4; ++i) {
            float a = sA[r0 + 16*i][k];
            acc[i].x += a * s4.x; acc[i].y += a * s4.y;
            acc[i].z += a * s4.z; acc[i].w += a * s4.w;
        }
    }
    #pragma unroll
    for (int i = 0; i < 4; ++i)
        *(float4*)(ln + base + (long)(r0 + 16*i) * 64 + o0) = acc[i];
}

// ------------------------------------------- one routing iteration (fused)
// grid 4096 (one block per batch) x 256 threads.
// WRITE_OUT=0: compute delta partial. WRITE_OUT=1: write final high.
template<int WRITE_OUT>
__global__ __launch_bounds__(256) void k_route(const float* __restrict__ ln_g,
                                               const int* __restrict__ seq_len,
                                               const float* __restrict__ Bc,
                                               float* __restrict__ partial,
                                               float* __restrict__ out) {
    __shared__ float ln_s[L_SZ][65];    // +1 pad: row-major, conflict-free both axes
    __shared__ float W_s[K_SZ][L_SZ];
    __shared__ float high_s[K_SZ][DOUTK];
    int t = threadIdx.x;
    int b = blockIdx.x;
    long lbase = (long)b * (L_SZ * DOUTK);

    // 1. stage low_new[b] (51.2 KB): coalesced float4 global reads
    {
        const float4* p = (const float4*)(ln_g + lbase);
        for (int j = t; j < (L_SZ * DOUTK / 4); j += 256) {
            float4 v = p[j];
            int f = j * 4; int r = f >> 6; int c = f & 63;
            ln_s[r][c] = v.x; ln_s[r][c+1] = v.y;
            ln_s[r][c+2] = v.z; ln_s[r][c+3] = v.w;
        }
    }
    int sl = seq_len[b];
    __syncthreads();

    // 2. masked softmax over L for row k (32 lanes per k)
    int k = t >> 5, g = t & 31;
    {
        const float* bk = Bc + k * L_SZ;
        float m = -3.4e38f;
        for (int l = g; l < sl; l += 32) m = fmaxf(m, bk[l]);
        #pragma unroll
        for (int s = 16; s > 0; s >>= 1) m = fmaxf(m, __shfl_xor(m, s, 32));
        float sum = 0.f;
        for (int l = g; l < L_SZ; l += 32) {
            float e = 0.f;
            if (l < sl) { e = __expf(bk[l] - m); sum += e; }
            W_s[k][l] = e;   // masked positions: exp(PAD-m) underflows to 0 exactly
        }
        #pragma unroll
        for (int s = 16; s > 0; s >>= 1) sum += __shfl_xor(sum, s, 32);
        float rinv = 1.0f / sum;
        for (int l = g; l < sl; l += 32) W_s[k][l] *= rinv;
    }
    __syncthreads();

    // 3. high[k][o] = sum_l W[k][l]*ln[l][o], then squash.  thread: (k, o=g, o=g+32)
    {
        float a0 = 0.f, a1 = 0.f;
        int o = g;
        for (int l = 0; l < sl; ++l) {          // W is 0 beyond sl
            float w = W_s[k][l];
            a0 += w * ln_s[l][o];
            a1 += w * ln_s[l][o + 32];
        }
        float nn = a0*a0 + a1*a1;
        #pragma unroll
        for (int s = 16; s > 0; s >>= 1) nn += __shfl_xor(nn, s, 32);
        float sc = nn / ((1.0f + nn) * sqrtf(nn + 1e-9f));
        a0 *= sc; a1 *= sc;
        if (WRITE_OUT) {
            float* ob = out + (long)b * (K_SZ * DOUTK) + k * DOUTK;
            ob[o] = a0; ob[o + 32] = a1;
        } else {
            high_s[k][o] = a0; high_s[k][o + 32] = a1;
        }
    }

    if (!WRITE_OUT) {
        __syncthreads();
        // 4. delta partial[k][l] = sum_o high[k][o]*ln[l][o]   (ALL l, unmasked!)
        if (t < L_SZ) {
            float* pb = partial + (long)b * (K_SZ * L_SZ);
            #pragma unroll
            for (int kk = 0; kk < K_SZ; ++kk) {
                float acc = 0.f;
                #pragma unroll 8
                for (int o = 0; o < DOUTK; ++o) acc += high_s[kk][o] * ln_s[t][o];
                pb[kk * L_SZ + t] = acc;
            }
        }
    }
}

// --------------------------------- deterministic tree-reduce of partials
// grid 50 x 256: each block owns 32 outputs, 8 sub-accumulators each.
__global__ __launch_bounds__(256) void k_reduce(const float* __restrict__ partial,
                                                float* __restrict__ Bc) {
    __shared__ float red[256];
    int t = threadIdx.x;
    int i = blockIdx.x * 32 + (t & 31);
    int sub = t >> 5;
    float s = 0.f;
    for (int p = sub; p < B_SZ; p += 8)
        s += partial[(long)p * (K_SZ * L_SZ) + i];
    red[t] = s;
    __syncthreads();
    for (int step = 4; step >= 1; step >>= 1) {
        if (sub < step) red[t] += red[t + step * 32];
        __syncthreads();
    }
    if (sub == 0) Bc[i] += red[t];
}

extern "C" void kernel_launch(void* const* d_in, const int* in_sizes, int n_in,
                              void* d_out, int out_size, void* d_ws, size_t ws_size,
                              hipStream_t stream) {
    const float* lc = (const float*)d_in[0];   // [4096,200,64]
    const int*   sl = (const int*)d_in[1];     // [4096,1]
    const float* Bm = (const float*)d_in[2];   // [1,8,200]
    const float* S  = (const float*)d_in[3];   // [64,64]
    float* out = (float*)d_out;                // [4096,8,64]
    float* ws  = (float*)d_ws;

    float* ln      = ws;                       // 52,428,800 floats
    float* Bc      = ws + 52428800L;           // 1,600 floats
    float* partial = Bc + 1600;                // 6,553,600 floats

    k_init  <<<7, 256, 0, stream>>>(Bm, Bc);
    k_matmul<<<(B_SZ * L_SZ) / 64, 256, 0, stream>>>(lc, S, ln);

    k_route<0><<<B_SZ, 256, 0, stream>>>(ln, sl, Bc, partial, out);
    k_reduce  <<<50, 256, 0, stream>>>(partial, Bc);
    k_route<0><<<B_SZ, 256, 0, stream>>>(ln, sl, Bc, partial, out);
    k_reduce  <<<50, 256, 0, stream>>>(partial, Bc);
    k_route<1><<<B_SZ, 256, 0, stream>>>(ln, sl, Bc, partial, out);
}

// Round 2
// 418.451 us; speedup vs baseline: 1.7374x; 1.7374x over previous
//
#include <hip/hip_runtime.h>
#include <math.h>

// CapsuleLayer dynamic routing, MI355X.
// B=4096, L=200, Din=Dout=64, K=8, 3 iterations.
//
// ws layout (floats):
//   ln      [B*L*64]  = 52,428,800   (low_new = lc @ S, materialized once)
//   Bc      [K*L]     = 1,600        (routing logits, updated per iteration)
//   partial [B*K*L]   = 6,553,600    (per-batch delta partials)
// partial2 [16*K*L] lives in d_out (fully overwritten by the final pass).

#define B_SZ  4096
#define L_SZ  200
#define DINK  64
#define DOUTK 64
#define K_SZ  8

// ---------------------------------------------------------------- init Bc
__global__ __launch_bounds__(256) void k_init(const float* __restrict__ Bm,
                                              float* __restrict__ Bc) {
    int i = blockIdx.x * 256 + threadIdx.x;
    if (i < K_SZ * L_SZ) Bc[i] = Bm[i];
}

// ------------------------------------------------- ln = lc @ S  (f32 VALU)
// grid 12800 blocks x 256 threads; each block does 64 rows.
__global__ __launch_bounds__(256) void k_matmul(const float* __restrict__ lc,
                                                const float* __restrict__ S,
                                                float* __restrict__ ln) {
    __shared__ float sS[64][64];
    __shared__ float sA[64][68];   // stride 68: 16B-aligned rows, reads 2-way max (free)
    int t = threadIdx.x;
    long base = (long)blockIdx.x * 64 * 64;

    {   // stage S (L2-hit after first blocks)
        const float4* S4 = (const float4*)S;
        float4* d = (float4*)&sS[0][0];
        for (int j = t; j < 1024; j += 256) d[j] = S4[j];
    }
    {   // stage lc tile: float4 in, float4 ds_write (68*4B row stride is 16B-mult)
        const float4* p = (const float4*)(lc + base);
        for (int j = t; j < 1024; j += 256) {
            int r = j >> 4, c4 = j & 15;
            *(float4*)&sA[r][c4 * 4] = p[j];
        }
    }
    __syncthreads();

    int o0 = (t & 15) * 4;        // 4 output cols
    int r0 = (t >> 4) * 4;        // 4 consecutive rows
    float4 acc[4] = {};
    for (int k4 = 0; k4 < 16; ++k4) {
        float4 a[4];
        #pragma unroll
        for (int i = 0; i < 4; ++i) a[i] = *(const float4*)&sA[r0 + i][k4 * 4];
        #pragma unroll
        for (int kk = 0; kk < 4; ++kk) {
            float4 s4 = *(const float4*)&sS[k4 * 4 + kk][o0];
            #pragma unroll
            for (int i = 0; i < 4; ++i) {
                float av = (kk == 0) ? a[i].x : (kk == 1) ? a[i].y
                         : (kk == 2) ? a[i].z : a[i].w;
                acc[i].x += av * s4.x; acc[i].y += av * s4.y;
                acc[i].z += av * s4.z; acc[i].w += av * s4.w;
            }
        }
    }
    #pragma unroll
    for (int i = 0; i < 4; ++i)
        *(float4*)(ln + base + (long)(r0 + i) * 64 + o0) = acc[i];
}

// ------------------------------------------- one routing iteration (fused)
// grid 4096 (one block per batch) x 256 threads.  NO ln LDS staging: ln[b]
// is 51.2KB and every k-group re-reads the same rows -> L1/L2 serves it.
// WRITE_OUT=0: compute delta partial. WRITE_OUT=1: write final high.
template<int WRITE_OUT>
__global__ __launch_bounds__(256) void k_route(const float* __restrict__ ln_g,
                                               const int* __restrict__ seq_len,
                                               const float* __restrict__ Bc,
                                               float* __restrict__ partial,
                                               float* __restrict__ out) {
    __shared__ float W_s[K_SZ][L_SZ];       // unnormalized exp(B-m)
    __shared__ float high_s[K_SZ][DOUTK];
    int t = threadIdx.x;
    int b = blockIdx.x;
    long lbase = (long)b * (L_SZ * DOUTK);
    const float2* ln2 = (const float2*)(ln_g + lbase);
    int sl = seq_len[b];
    int k = t >> 5, g = t & 31;

    // 1. masked softmax stats over L for row k (32 lanes per k)
    const float* bk = Bc + k * L_SZ;
    float m = -3.4e38f;
    for (int l = g; l < sl; l += 32) m = fmaxf(m, bk[l]);
    #pragma unroll
    for (int s = 16; s > 0; s >>= 1) m = fmaxf(m, __shfl_xor(m, s, 32));
    float sum = 0.f;
    for (int l = g; l < sl; l += 32) {
        float e = __expf(bk[l] - m);
        sum += e;
        W_s[k][l] = e;                      // normalization folded into step 2
    }
    #pragma unroll
    for (int s = 16; s > 0; s >>= 1) sum += __shfl_xor(sum, s, 32);
    float rinv = 1.0f / sum;
    __syncthreads();

    // 2. high[k][o] = rinv * sum_l W[k][l]*ln[l][o]; squash.  thread: (k, o=2g,2g+1)
    {
        float a0 = 0.f, a1 = 0.f;
        for (int l = 0; l < sl; ++l) {
            float w = W_s[k][l];            // same-address broadcast: free
            float2 v = ln2[l * 32 + g];     // wave-halves read identical 256B rows
            a0 += w * v.x; a1 += w * v.y;
        }
        a0 *= rinv; a1 *= rinv;
        float nn = a0 * a0 + a1 * a1;
        #pragma unroll
        for (int s = 16; s > 0; s >>= 1) nn += __shfl_xor(nn, s, 32);
        float sc = nn / ((1.0f + nn) * sqrtf(nn + 1e-9f));
        a0 *= sc; a1 *= sc;
        if (WRITE_OUT) {
            float2* ob2 = (float2*)(out + (long)b * (K_SZ * DOUTK) + k * DOUTK);
            ob2[g] = make_float2(a0, a1);
        } else {
            *(float2*)&high_s[k][2 * g] = make_float2(a0, a1);
        }
    }

    if (!WRITE_OUT) {
        __syncthreads();
        // 3. delta partial[k][l] = sum_o high[k][o]*ln[l][o]  (ALL l, unmasked)
        if (t < L_SZ) {
            const float4* row4 = (const float4*)(ln_g + lbase + (long)t * 64);
            float* pb = partial + (long)b * (K_SZ * L_SZ);
            float acc[K_SZ] = {};
            #pragma unroll
            for (int o4 = 0; o4 < 16; ++o4) {
                float4 v = row4[o4];        // L1-hot from step 2
                #pragma unroll
                for (int kk = 0; kk < K_SZ; ++kk) {
                    float4 h = *(const float4*)&high_s[kk][o4 * 4];  // b128 broadcast
                    acc[kk] += v.x * h.x + v.y * h.y + v.z * h.z + v.w * h.w;
                }
            }
            #pragma unroll
            for (int kk = 0; kk < K_SZ; ++kk)
                pb[kk * L_SZ + t] = acc[kk];    // coalesced over t
        }
    }
}

// --------------------------- deterministic two-stage reduce of partials
// Stage A: grid 800 = 50 col-groups x 16 batch-chunks; coalesced 128B reads.
__global__ __launch_bounds__(256) void k_reduceA(const float* __restrict__ partial,
                                                 float* __restrict__ partial2) {
    __shared__ float red[256];
    int x = blockIdx.x % 50;       // 32-output group
    int y = blockIdx.x / 50;       // 256-batch chunk
    int t = threadIdx.x;
    int i = x * 32 + (t & 31);
    int sub = t >> 5;
    float s = 0.f;
    for (int p = y * 256 + sub; p < (y + 1) * 256; p += 8)
        s += partial[(long)p * (K_SZ * L_SZ) + i];
    red[t] = s;
    __syncthreads();
    for (int step = 4; step >= 1; step >>= 1) {
        if (sub < step) red[t] += red[t + step * 32];
        __syncthreads();
    }
    if (sub == 0) partial2[y * (K_SZ * L_SZ) + i] = red[t];
}

// Stage B: fold 16 chunk-partials into Bc. grid 7 x 256.
__global__ __launch_bounds__(256) void k_reduceB(const float* __restrict__ partial2,
                                                 float* __restrict__ Bc) {
    int i = blockIdx.x * 256 + threadIdx.x;
    if (i < K_SZ * L_SZ) {
        float s = 0.f;
        #pragma unroll
        for (int y = 0; y < 16; ++y) s += partial2[y * (K_SZ * L_SZ) + i];
        Bc[i] += s;
    }
}

extern "C" void kernel_launch(void* const* d_in, const int* in_sizes, int n_in,
                              void* d_out, int out_size, void* d_ws, size_t ws_size,
                              hipStream_t stream) {
    const float* lc = (const float*)d_in[0];   // [4096,200,64]
    const int*   sl = (const int*)d_in[1];     // [4096,1]
    const float* Bm = (const float*)d_in[2];   // [1,8,200]
    const float* S  = (const float*)d_in[3];   // [64,64]
    float* out = (float*)d_out;                // [4096,8,64]
    float* ws  = (float*)d_ws;

    float* ln      = ws;                       // 52,428,800 floats
    float* Bc      = ws + 52428800L;           // 1,600 floats
    float* partial = Bc + 1600;                // 6,553,600 floats
    float* p2      = out;                      // scratch: overwritten by final pass

    k_init  <<<7, 256, 0, stream>>>(Bm, Bc);
    k_matmul<<<(B_SZ * L_SZ) / 64, 256, 0, stream>>>(lc, S, ln);

    k_route<0><<<B_SZ, 256, 0, stream>>>(ln, sl, Bc, partial, out);
    k_reduceA <<<800, 256, 0, stream>>>(partial, p2);
    k_reduceB <<<7, 256, 0, stream>>>(p2, Bc);
    k_route<0><<<B_SZ, 256, 0, stream>>>(ln, sl, Bc, partial, out);
    k_reduceA <<<800, 256, 0, stream>>>(partial, p2);
    k_reduceB <<<7, 256, 0, stream>>>(p2, Bc);
    k_route<1><<<B_SZ, 256, 0, stream>>>(ln, sl, Bc, partial, out);
}

// Round 3
// 304.440 us; speedup vs baseline: 2.3881x; 1.3745x over previous
//
#include <hip/hip_runtime.h>
#include <math.h>

// CapsuleLayer dynamic routing, MI355X.
// B=4096, L=200, Din=Dout=64, K=8, 3 iterations.
//
// Key identity: low_new = lc @ S never needs materializing.
//   high_pre = W @ (lc@S) = (W@lc) @ S        (hp then tiny projection)
//   delta    = high @ (lc@S)^T = (high@S^T) @ lc^T  (hs then row dots)
// So the only big array ever touched is lc (210 MB, fits 256 MB L3).
//
// ws layout (floats):
//   Bc      [K*L]   = 1,600        (routing logits, updated per iteration)
//   partial [B*K*L] = 6,553,600    (per-batch delta partials)
// partial2 [16*K*L] lives in d_out (fully overwritten by the final pass).

#define B_SZ  4096
#define L_SZ  200
#define DINK  64
#define DOUTK 64
#define K_SZ  8

// ---------------------------------------------------------------- init Bc
__global__ __launch_bounds__(256) void k_init(const float* __restrict__ Bm,
                                              float* __restrict__ Bc) {
    int i = blockIdx.x * 256 + threadIdx.x;
    if (i < K_SZ * L_SZ) Bc[i] = Bm[i];
}

// ------------------------------------------- one routing iteration (fused)
// grid 4096 (one block per batch) x 256 threads.
// WRITE_OUT=0: compute delta partial. WRITE_OUT=1: write final high.
template<int WRITE_OUT>
__global__ __launch_bounds__(256) void k_route(const float* __restrict__ lc_g,
                                               const int* __restrict__ seq_len,
                                               const float* __restrict__ S_g,
                                               const float* __restrict__ Bc,
                                               float* __restrict__ partial,
                                               float* __restrict__ out) {
    __shared__ float W_s[K_SZ][L_SZ];      // 6.4 KB  unnormalized exp(B-m)
    __shared__ float Ss[64][65];           // 16.6 KB S, +1 pad: rows AND cols 2-way max
    __shared__ float hp_s[K_SZ][DINK];     // 2 KB    W@lc (normalized)
    __shared__ float hx_s[K_SZ][DOUTK];    // 2 KB    high (squashed)
    __shared__ float hs_s[K_SZ][DINK];     // 2 KB    high@S^T
    int t = threadIdx.x;
    int b = blockIdx.x;
    long lbase = (long)b * (L_SZ * DINK);
    const float2* lc2 = (const float2*)(lc_g + lbase);
    int sl = seq_len[b];
    int k = t >> 5, g = t & 31;

    // 0. stage S (16 KB, L2-hot): coalesced float4 in, scalar scatter to padded rows
    {
        const float4* S4 = (const float4*)S_g;
        for (int j = t; j < 1024; j += 256) {
            float4 v = S4[j];
            int r = j >> 4, c = (j & 15) * 4;
            Ss[r][c] = v.x; Ss[r][c+1] = v.y; Ss[r][c+2] = v.z; Ss[r][c+3] = v.w;
        }
    }

    // 1. masked softmax stats over L for row k (32 lanes per k)
    const float* bk = Bc + k * L_SZ;
    float m = -3.4e38f;
    for (int l = g; l < sl; l += 32) m = fmaxf(m, bk[l]);
    #pragma unroll
    for (int s = 16; s > 0; s >>= 1) m = fmaxf(m, __shfl_xor(m, s, 32));
    float sum = 0.f;
    for (int l = g; l < sl; l += 32) {
        float e = __expf(bk[l] - m);
        sum += e;
        W_s[k][l] = e;                      // normalization folded into step 2
    }
    #pragma unroll
    for (int s = 16; s > 0; s >>= 1) sum += __shfl_xor(sum, s, 32);
    float rinv = 1.0f / sum;
    __syncthreads();

    // 2. hp[k][i] = rinv * sum_l W[k][l]*lc[l][i]   thread: (k, i=2g,2g+1)
    {
        float a0 = 0.f, a1 = 0.f;
        for (int l = 0; l < sl; ++l) {
            float w = W_s[k][l];            // same-address broadcast: free
            float2 v = lc2[l * 32 + g];     // wave-halves read identical 256B rows
            a0 += w * v.x; a1 += w * v.y;
        }
        *(float2*)&hp_s[k][2 * g] = make_float2(a0 * rinv, a1 * rinv);
    }
    __syncthreads();

    // 3. high[k][o] = sum_i hp[k][i]*S[i][o]; squash.  thread: (k, o=2g,2g+1)
    {
        float h0 = 0.f, h1 = 0.f;
        #pragma unroll 8
        for (int i = 0; i < DINK; ++i) {
            float p = hp_s[k][i];                         // broadcast
            float2 sv = *(const float2*)&Ss[i][2 * g];    // b64, 2-way banks
            h0 += p * sv.x; h1 += p * sv.y;
        }
        float nn = h0 * h0 + h1 * h1;
        #pragma unroll
        for (int s = 16; s > 0; s >>= 1) nn += __shfl_xor(nn, s, 32);
        float sc = nn / ((1.0f + nn) * sqrtf(nn + 1e-9f));
        h0 *= sc; h1 *= sc;
        if (WRITE_OUT) {
            float2* ob2 = (float2*)(out + (long)b * (K_SZ * DOUTK) + k * DOUTK);
            ob2[g] = make_float2(h0, h1);
            return;
        }
        *(float2*)&hx_s[k][2 * g] = make_float2(h0, h1);
    }
    __syncthreads();

    // 4. hs[k][i] = sum_o high[k][o]*S[i][o]   thread: (k, i=2g,2g+1)
    {
        float s0 = 0.f, s1 = 0.f;
        int i0 = 2 * g, i1 = 2 * g + 1;
        #pragma unroll 8
        for (int o = 0; o < DOUTK; ++o) {
            float hv = hx_s[k][o];          // broadcast
            s0 += hv * Ss[i0][o];           // 2-way banks
            s1 += hv * Ss[i1][o];
        }
        *(float2*)&hs_s[k][2 * g] = make_float2(s0, s1);
    }
    __syncthreads();

    // 5. delta partial[k][l] = sum_i hs[k][i]*lc[l][i]  (ALL l, unmasked)
    if (t < L_SZ) {
        const float4* row4 = (const float4*)(lc_g + lbase + (long)t * DINK);
        float* pb = partial + (long)b * (K_SZ * L_SZ);
        float acc[K_SZ] = {};
        #pragma unroll
        for (int i4 = 0; i4 < 16; ++i4) {
            float4 v = row4[i4];            // L1/L2-hot from step 2
            #pragma unroll
            for (int kk = 0; kk < K_SZ; ++kk) {
                float4 h = *(const float4*)&hs_s[kk][i4 * 4];  // b128 broadcast
                acc[kk] += v.x * h.x + v.y * h.y + v.z * h.z + v.w * h.w;
            }
        }
        #pragma unroll
        for (int kk = 0; kk < K_SZ; ++kk)
            pb[kk * L_SZ + t] = acc[kk];    // coalesced over t
    }
}

// --------------------------- deterministic two-stage reduce of partials
// Stage A: grid 800 = 50 col-groups x 16 batch-chunks; coalesced 128B reads.
__global__ __launch_bounds__(256) void k_reduceA(const float* __restrict__ partial,
                                                 float* __restrict__ partial2) {
    __shared__ float red[256];
    int x = blockIdx.x % 50;       // 32-output group
    int y = blockIdx.x / 50;       // 256-batch chunk
    int t = threadIdx.x;
    int i = x * 32 + (t & 31);
    int sub = t >> 5;
    float s = 0.f;
    for (int p = y * 256 + sub; p < (y + 1) * 256; p += 8)
        s += partial[(long)p * (K_SZ * L_SZ) + i];
    red[t] = s;
    __syncthreads();
    for (int step = 4; step >= 1; step >>= 1) {
        if (sub < step) red[t] += red[t + step * 32];
        __syncthreads();
    }
    if (sub == 0) partial2[y * (K_SZ * L_SZ) + i] = red[t];
}

// Stage B: fold 16 chunk-partials into Bc. grid 7 x 256.
__global__ __launch_bounds__(256) void k_reduceB(const float* __restrict__ partial2,
                                                 float* __restrict__ Bc) {
    int i = blockIdx.x * 256 + threadIdx.x;
    if (i < K_SZ * L_SZ) {
        float s = 0.f;
        #pragma unroll
        for (int y = 0; y < 16; ++y) s += partial2[y * (K_SZ * L_SZ) + i];
        Bc[i] += s;
    }
}

extern "C" void kernel_launch(void* const* d_in, const int* in_sizes, int n_in,
                              void* d_out, int out_size, void* d_ws, size_t ws_size,
                              hipStream_t stream) {
    const float* lc = (const float*)d_in[0];   // [4096,200,64]
    const int*   sl = (const int*)d_in[1];     // [4096,1]
    const float* Bm = (const float*)d_in[2];   // [1,8,200]
    const float* S  = (const float*)d_in[3];   // [64,64]
    float* out = (float*)d_out;                // [4096,8,64]
    float* ws  = (float*)d_ws;

    float* Bc      = ws;                       // 1,600 floats
    float* partial = ws + 1600;                // 6,553,600 floats
    float* p2      = out;                      // scratch: overwritten by final pass

    k_init<<<7, 256, 0, stream>>>(Bm, Bc);

    k_route<0><<<B_SZ, 256, 0, stream>>>(lc, sl, S, Bc, partial, out);
    k_reduceA <<<800, 256, 0, stream>>>(partial, p2);
    k_reduceB <<<7, 256, 0, stream>>>(p2, Bc);
    k_route<0><<<B_SZ, 256, 0, stream>>>(lc, sl, S, Bc, partial, out);
    k_reduceA <<<800, 256, 0, stream>>>(partial, p2);
    k_reduceB <<<7, 256, 0, stream>>>(p2, Bc);
    k_route<1><<<B_SZ, 256, 0, stream>>>(lc, sl, S, Bc, partial, out);
}